// Round 3
// baseline (140.376 us; speedup 1.0000x reference)
//
#include <hip/hip_runtime.h>
#include <math.h>

#define CC 8
#define PP 169
#define KTOT 100
#define WW 128
#define HWSZ (128*128)
#define KCH 5           // instances per block chunk (100 = 20 chunks)
#define PXT 4           // pixels per thread

// All weight reads are wave-uniform (instance index block-uniform, ind[] load
// uniform, gather addresses uniform) -> compiler emits s_load; weights live in
// SGPRs and each FMA is v_fma_f32 vdst, sgpr, vgpr, vgpr. No LDS at all.

__global__ __launch_bounds__(256, 5) void condinst_kernel(
    const float* __restrict__ seg_feat,     // (B, C, HW)
    const float* __restrict__ conv_weight,  // (B, P, HW)
    const int*   __restrict__ ind,          // (B, K)
    float*       __restrict__ out)          // (B, K, HW)
{
    const int tile = blockIdx.x;   // 0..15   (1024 px per block)
    const int b    = blockIdx.y;   // 0..3
    const int k0   = blockIdx.z * KCH;

    const int px0 = tile * (256 * PXT) + threadIdx.x * PXT;

    // ---- per-thread pixel state, loaded once ----
    float ff[CC][PXT];
    #pragma unroll
    for (int c = 0; c < CC; ++c) {
        float4 v = *(const float4*)&seg_feat[(size_t)(b * CC + c) * HWSZ + px0];
        ff[c][0] = v.x; ff[c][1] = v.y; ff[c][2] = v.z; ff[c][3] = v.w;
    }
    float xp[PXT];
    const float x0 = (float)(px0 & (WW - 1));   // px0 % 4 == 0 -> same row
    #pragma unroll
    for (int t = 0; t < PXT; ++t) xp[t] = x0 + (float)t;
    const float yp = (float)(px0 >> 7);

    for (int k = 0; k < KCH; ++k) {
        const int inst = k0 + k;
        const int hw = ind[b * KTOT + inst];            // uniform -> s_load
        const float sx = (float)(hw & (WW - 1));
        const float sy = (float)(hw >> 7);
        const float* __restrict__ p = conv_weight + (size_t)b * PP * HWSZ + hw;
        // weight j lives at p[j*HWSZ]; j compile-time -> uniform addr -> s_load
        #define W(j) p[(size_t)(j) * HWSZ]

        float rx[PXT];
        #pragma unroll
        for (int t = 0; t < PXT; ++t) rx[t] = (sx - xp[t]) * 0.0078125f;
        const float ry = (sy - yp) * 0.0078125f;

        // ---- layer 0: 10 -> 8, relu (o-outer, t-inner) ----
        float h0[CC][PXT];
        #pragma unroll
        for (int o = 0; o < CC; ++o) {
            const float wx = W(o * 10 + 0);
            const float wy = W(o * 10 + 1);
            const float w2c = W(o * 10 + 2), w3c = W(o * 10 + 3);
            const float w4c = W(o * 10 + 4), w5c = W(o * 10 + 5);
            const float w6c = W(o * 10 + 6), w7c = W(o * 10 + 7);
            const float w8c = W(o * 10 + 8), w9c = W(o * 10 + 9);
            const float bb = W(152 + o);
            #pragma unroll
            for (int t = 0; t < PXT; ++t) {
                float a = fmaf(wx, rx[t], bb);
                a = fmaf(wy, ry, a);
                a = fmaf(w2c, ff[0][t], a);
                a = fmaf(w3c, ff[1][t], a);
                a = fmaf(w4c, ff[2][t], a);
                a = fmaf(w5c, ff[3][t], a);
                a = fmaf(w6c, ff[4][t], a);
                a = fmaf(w7c, ff[5][t], a);
                a = fmaf(w8c, ff[6][t], a);
                a = fmaf(w9c, ff[7][t], a);
                h0[o][t] = fmaxf(a, 0.0f);
            }
        }

        // ---- layers 1+2, t-outer to cap liveness (h1 is 8 regs) ----
        float4 res;
        float* resp = (float*)&res;
        #pragma unroll
        for (int t = 0; t < PXT; ++t) {
            float h1[CC];
            #pragma unroll
            for (int o = 0; o < CC; ++o) {
                float a = W(160 + o);
                #pragma unroll
                for (int c = 0; c < CC; ++c)
                    a = fmaf(W(80 + o * 8 + c), h0[c][t], a);
                h1[o] = fmaxf(a, 0.0f);
            }
            float z = W(168);
            #pragma unroll
            for (int c = 0; c < CC; ++c)
                z = fmaf(W(144 + c), h1[c], z);
            resp[t] = 1.0f / (1.0f + __expf(-z));
        }
        #undef W

        *(float4*)&out[(size_t)(b * KTOT + inst) * HWSZ + px0] = res;
    }
}

extern "C" void kernel_launch(void* const* d_in, const int* in_sizes, int n_in,
                              void* d_out, int out_size, void* d_ws, size_t ws_size,
                              hipStream_t stream) {
    const float* seg_feat    = (const float*)d_in[0];
    const float* conv_weight = (const float*)d_in[1];
    const int*   ind         = (const int*)d_in[2];
    float*       out         = (float*)d_out;

    dim3 grid(16, 4, 20);   // 16 pixel tiles x B x 20 k-chunks = 1280 blocks
    dim3 block(256);
    condinst_kernel<<<grid, block, 0, stream>>>(seg_feat, conv_weight, ind, out);
}

// Round 4
// 49.573 us; speedup vs baseline: 2.8317x; 2.8317x over previous
//
#include <hip/hip_runtime.h>
#include <math.h>

#define CC 8
#define PP 169
#define KTOT 100
#define WW 128
#define HWSZ (128*128)
#define KCH 5           // instances per compute-block chunk (100 = 20 chunks)
#define PXT 4           // pixels per thread
#define FPI 192         // packed floats per instance (768 B, 64B-aligned)

// packed per-instance layout (FPI floats):
//  [0:80)    w0 (8 x 10) row-major
//  [80:88)   b0
//  [88:152)  w1 (8 x 8) row-major
//  [152:160) b1
//  [160:168) w2
//  [168]     b2
//  [169]     sx   [170] sy   [171:192) pad

__global__ __launch_bounds__(256) void pack_kernel(
    const float* __restrict__ conv_weight,  // (B, P, HW)
    const int*   __restrict__ ind,          // (B, K) flat
    float*       __restrict__ pw)           // (400, FPI)
{
    const int id = blockIdx.x * 256 + threadIdx.x;
    if (id >= 4 * KTOT * FPI) return;
    const int n = id / FPI;
    const int j = id - n * FPI;
    const int b = n / KTOT;
    const int hw = ind[n];
    float v = 0.0f;
    if (j < 169) {
        int p;
        if (j < 80)       p = j;                  // w0
        else if (j < 88)  p = 152 + (j - 80);     // b0
        else if (j < 152) p = 80 + (j - 88);      // w1
        else if (j < 160) p = 160 + (j - 152);    // b1
        else if (j < 168) p = 144 + (j - 160);    // w2
        else              p = 168;                // b2
        v = conv_weight[(size_t)(b * PP + p) * HWSZ + hw];
    } else if (j == 169) {
        v = (float)(hw & (WW - 1));
    } else if (j == 170) {
        v = (float)(hw >> 7);
    }
    pw[id] = v;
}

__global__ __launch_bounds__(256, 5) void condinst_kernel(
    const float* __restrict__ seg_feat,     // (B, C, HW)
    const float* __restrict__ pw,           // (400, FPI) packed params
    float*       __restrict__ out)          // (B, K, HW)
{
    const int tile = blockIdx.x;   // 0..15   (1024 px per block)
    const int b    = blockIdx.y;   // 0..3
    const int k0   = blockIdx.z * KCH;

    const int px0 = tile * (256 * PXT) + threadIdx.x * PXT;

    // ---- per-thread pixel state, loaded once ----
    float ff[CC][PXT];
    #pragma unroll
    for (int c = 0; c < CC; ++c) {
        float4 v = *(const float4*)&seg_feat[(size_t)(b * CC + c) * HWSZ + px0];
        ff[c][0] = v.x; ff[c][1] = v.y; ff[c][2] = v.z; ff[c][3] = v.w;
    }
    const float x0 = (float)(px0 & (WW - 1));   // px0 % 4 == 0 -> same row
    const float yp = (float)(px0 >> 7);

    for (int k = 0; k < KCH; ++k) {
        const int inst = b * KTOT + k0 + k;
        const float* __restrict__ p = pw + (size_t)inst * FPI;  // block-uniform -> s_load

        const float sx = p[169];
        const float sy = p[170];
        float rx[PXT];
        #pragma unroll
        for (int t = 0; t < PXT; ++t) rx[t] = (sx - (x0 + (float)t)) * 0.0078125f;
        const float ry = (sy - yp) * 0.0078125f;

        // ---- layer 0: 10 -> 8, relu (o-outer, t-inner) ----
        float h0[CC][PXT];
        #pragma unroll
        for (int o = 0; o < CC; ++o) {
            const float wx = p[o * 10 + 0];
            const float wy = p[o * 10 + 1];
            const float w2c = p[o * 10 + 2], w3c = p[o * 10 + 3];
            const float w4c = p[o * 10 + 4], w5c = p[o * 10 + 5];
            const float w6c = p[o * 10 + 6], w7c = p[o * 10 + 7];
            const float w8c = p[o * 10 + 8], w9c = p[o * 10 + 9];
            const float bb = p[80 + o];
            #pragma unroll
            for (int t = 0; t < PXT; ++t) {
                float a = fmaf(wx, rx[t], bb);
                a = fmaf(wy, ry, a);
                a = fmaf(w2c, ff[0][t], a);
                a = fmaf(w3c, ff[1][t], a);
                a = fmaf(w4c, ff[2][t], a);
                a = fmaf(w5c, ff[3][t], a);
                a = fmaf(w6c, ff[4][t], a);
                a = fmaf(w7c, ff[5][t], a);
                a = fmaf(w8c, ff[6][t], a);
                a = fmaf(w9c, ff[7][t], a);
                h0[o][t] = fmaxf(a, 0.0f);
            }
        }

        // ---- layers 1+2, t-outer to cap liveness (h1 is 8 regs) ----
        float4 res;
        float* resp = (float*)&res;
        #pragma unroll
        for (int t = 0; t < PXT; ++t) {
            float h1[CC];
            #pragma unroll
            for (int o = 0; o < CC; ++o) {
                float a = p[152 + o];
                #pragma unroll
                for (int c = 0; c < CC; ++c)
                    a = fmaf(p[88 + o * 8 + c], h0[c][t], a);
                h1[o] = fmaxf(a, 0.0f);
            }
            float z = p[168];
            #pragma unroll
            for (int c = 0; c < CC; ++c)
                z = fmaf(p[160 + c], h1[c], z);
            resp[t] = 1.0f / (1.0f + __expf(-z));
        }

        *(float4*)&out[(size_t)inst * HWSZ + px0] = res;
    }
}

extern "C" void kernel_launch(void* const* d_in, const int* in_sizes, int n_in,
                              void* d_out, int out_size, void* d_ws, size_t ws_size,
                              hipStream_t stream) {
    const float* seg_feat    = (const float*)d_in[0];
    const float* conv_weight = (const float*)d_in[1];
    const int*   ind         = (const int*)d_in[2];
    float*       out         = (float*)d_out;
    float*       pw          = (float*)d_ws;   // 400*192*4 = 307200 B

    {
        int total = 4 * KTOT * FPI;
        dim3 grid((total + 255) / 256), block(256);
        pack_kernel<<<grid, block, 0, stream>>>(conv_weight, ind, pw);
    }
    {
        dim3 grid(16, 4, 20), block(256);   // 1280 blocks = 5 per CU
        condinst_kernel<<<grid, block, 0, stream>>>(seg_feat, pw, out);
    }
}